// Round 7
// baseline (299.502 us; speedup 1.0000x reference)
//
#include <hip/hip_runtime.h>
#include <hip/hip_bf16.h>

// Shapes: B=1024, C=80, D_WORD=300 (pad 384), J=8000, IMG_CH=2048
// out = feature @ H^T + r;  H = P @ W_img;  r = P @ b_img
// P = x2 @ W_cls^T + b_cls; x2 = y @ Wgc2; y = adj @ leaky(adj @ (x0 @ Wgc1))
// R7: register-prefetch streamed weights (latency), 12 -> 9 dispatches (~12us/launch),
//     no global atomics (R5 lesson: atomicAdd writes through to HBM at 4B).

typedef __bf16 bf16_t;
typedef __bf16 bf16x8 __attribute__((ext_vector_type(8)));
typedef float f32x4 __attribute__((ext_vector_type(4)));

#define MFMA16(a, b, c) __builtin_amdgcn_mfma_f32_16x16x32_bf16((a), (b), (c), 0, 0, 0)

__device__ inline bf16x8 cvt8(float4 a, float4 b) {
  bf16x8 v;
  v[0] = (bf16_t)a.x; v[1] = (bf16_t)a.y; v[2] = (bf16_t)a.z; v[3] = (bf16_t)a.w;
  v[4] = (bf16_t)b.x; v[5] = (bf16_t)b.y; v[6] = (bf16_t)b.z; v[7] = (bf16_t)b.w;
  return v;
}

// ---- setup: bid0 = adj + zero r; bid 1..120 = x0b pad-convert ----
__global__ __launch_bounds__(256) void k_setup(
    const float* __restrict__ A, const float* __restrict__ inp0,
    float* __restrict__ adj, float* __restrict__ r, bf16_t* __restrict__ x0b) {
  int tid = threadIdx.x, bid = blockIdx.x;
  if (bid == 0) {
    __shared__ float Dv[80];
    if (tid < 80) {
      float s = 0.f;
      #pragma unroll 4
      for (int j = 0; j < 80; ++j) s += A[tid * 80 + j];
      Dv[tid] = rsqrtf(s);
      r[tid] = 0.f;
    }
    __syncthreads();
    for (int idx = tid; idx < 6400; idx += 256) {
      int i = idx / 80, j = idx % 80;
      adj[idx] = Dv[i] * Dv[j] * A[j * 80 + i];
    }
  } else {
    int idx = (bid - 1) * 256 + tid;  // 80*384 = 30720 = 120*256
    int c = idx / 384, k = idx % 384;
    x0b[idx] = (k < 300) ? (bf16_t)inp0[c * 300 + k] : (bf16_t)0.f;
  }
}

// ---- t1 = x0 @ Wgc1 : [80,1024], K=300 padded to 384 ---- (R6 verbatim)
__global__ __launch_bounds__(256) void k_gc1m(
    const bf16_t* __restrict__ x0b, const float* __restrict__ Wgc1,
    float* __restrict__ t1) {
  int tid = threadIdx.x;
  int w = tid >> 6, l = tid & 63;
  int ln = l & 15, q = l >> 4;
  int n0 = blockIdx.x * 16;

  __shared__ float red[4][80][16];
  f32x4 acc[5] = {};
  for (int ks = 0; ks < 3; ++ks) {
    int kq = w * 96 + ks * 32 + q * 8;
    bf16x8 bfrag;
    #pragma unroll
    for (int jj = 0; jj < 8; ++jj) {
      int k = kq + jj;
      int kc = k < 300 ? k : 299;
      float wv = Wgc1[kc * 1024 + n0 + ln];
      bfrag[jj] = (bf16_t)(k < 300 ? wv : 0.f);
    }
    #pragma unroll
    for (int mt = 0; mt < 5; ++mt) {
      bf16x8 afrag = *(const bf16x8*)(x0b + (size_t)(mt * 16 + ln) * 384 + kq);
      acc[mt] = MFMA16(afrag, bfrag, acc[mt]);
    }
  }
  #pragma unroll
  for (int mt = 0; mt < 5; ++mt)
    #pragma unroll
    for (int reg = 0; reg < 4; ++reg)
      red[w][mt * 16 + q * 4 + reg][ln] = acc[mt][reg];
  __syncthreads();
  for (int o = tid; o < 1280; o += 256) {
    int c = o >> 4, nn = o & 15;
    t1[c * 1024 + n0 + nn] = red[0][c][nn] + red[1][c][nn] + red[2][c][nn] + red[3][c][nn];
  }
}

// ---- y = bf16(adj @ leaky_relu(adj @ t1)) : [80,1024]; fused double adj-mul ----
// grid 16 (n-chunks of 64); all column-local, LDS-staged
__global__ __launch_bounds__(256) void k_adj2(
    const float* __restrict__ adj, const float* __restrict__ t1,
    bf16_t* __restrict__ y) {
  int tid = threadIdx.x;
  int n0 = blockIdx.x * 64;
  __shared__ float adjS[80][80];  // 25.6 KB
  __shared__ float aS[80][64];    // 20 KB
  __shared__ float bS[80][64];    // 20 KB
  for (int i = tid; i < 6400; i += 256) adjS[i / 80][i % 80] = adj[i];
  for (int i = tid; i < 5120; i += 256) {
    int c = i >> 6, nn = i & 63;
    aS[c][nn] = t1[c * 1024 + n0 + nn];
  }
  __syncthreads();
  for (int i = tid; i < 5120; i += 256) {
    int c = i >> 6, nn = i & 63;
    float s = 0.f;
    #pragma unroll 4
    for (int cc = 0; cc < 80; ++cc) s += adjS[c][cc] * aS[cc][nn];
    bS[c][nn] = s > 0.f ? s : 0.2f * s;
  }
  __syncthreads();
  for (int i = tid; i < 5120; i += 256) {
    int c = i >> 6, nn = i & 63;
    float s = 0.f;
    #pragma unroll 4
    for (int cc = 0; cc < 80; ++cc) s += adjS[c][cc] * bS[cc][nn];
    y[c * 1024 + n0 + nn] = (bf16_t)s;
  }
}

// ---- t2p[kc] = y @ Wgc2 k-slice : grid 256 = 32 nc x 8 kc ---- (R6 verbatim, input y)
__global__ __launch_bounds__(256) void k_gc2m(
    const bf16_t* __restrict__ y, const float* __restrict__ Wgc2,
    float* __restrict__ t2p) {
  int tid = threadIdx.x;
  int w = tid >> 6, l = tid & 63;
  int ln = l & 15, q = l >> 4;
  int nc = blockIdx.x & 31, kc = blockIdx.x >> 5;  // kc 0..7
  const float* wbase = Wgc2 + (size_t)(kc * 128) * 2048 + nc * 64;

  __shared__ float Bs[2][32][66];
  float4 pv[2];
  #pragma unroll
  for (int it = 0; it < 2; ++it) {
    int slot = tid + it * 256, kr = slot >> 4, nq = slot & 15;
    pv[it] = *(const float4*)(wbase + (size_t)kr * 2048 + nq * 4);
  }
  f32x4 acc[5] = {};
  for (int s = 0; s < 4; ++s) {
    #pragma unroll
    for (int it = 0; it < 2; ++it) {
      int slot = tid + it * 256, kr = slot >> 4, nq = slot & 15;
      *(float4*)&Bs[s & 1][kr][nq * 4] = pv[it];
    }
    __syncthreads();
    if (s < 3) {
      #pragma unroll
      for (int it = 0; it < 2; ++it) {
        int slot = tid + it * 256, kr = slot >> 4, nq = slot & 15;
        pv[it] = *(const float4*)(wbase + (size_t)((s + 1) * 32 + kr) * 2048 + nq * 4);
      }
    }
    int k0 = kc * 128 + s * 32;
    bf16x8 bfrag;
    #pragma unroll
    for (int jj = 0; jj < 8; ++jj) bfrag[jj] = (bf16_t)Bs[s & 1][q * 8 + jj][w * 16 + ln];
    #pragma unroll
    for (int mt = 0; mt < 5; ++mt) {
      bf16x8 afrag = *(const bf16x8*)(y + (size_t)(mt * 16 + ln) * 1024 + k0 + q * 8);
      acc[mt] = MFMA16(afrag, bfrag, acc[mt]);
    }
  }
  float* tp = t2p + (size_t)kc * 163840 + nc * 64 + w * 16 + ln;
  #pragma unroll
  for (int mt = 0; mt < 5; ++mt)
    #pragma unroll
    for (int reg = 0; reg < 4; ++reg)
      tp[(size_t)(mt * 16 + q * 4 + reg) * 2048] = acc[mt][reg];
}

// ---- x2 = bf16(sum_8 t2p) ----
__global__ void k_redcvt(const float* __restrict__ t2p, bf16_t* __restrict__ x2) {
  int i = blockIdx.x * 256 + threadIdx.x;  // 163840
  float s = 0.f;
  #pragma unroll
  for (int p = 0; p < 8; ++p) s += t2p[(size_t)p * 163840 + i];
  x2[i] = (bf16_t)s;
}

// ---- P = bf16(x2 @ W_cls^T + b_cls); r[c] += b_img . P[c,:] ----
// register-prefetch all 16 float4 of Wcls per thread (latency fix)
__global__ __launch_bounds__(512) void k_clsproj(
    const float* __restrict__ Wcls, const float* __restrict__ bcls,
    const float* __restrict__ bimg, const bf16_t* __restrict__ x2,
    bf16_t* __restrict__ P, float* __restrict__ r) {
  int tid = threadIdx.x;
  int w = tid >> 6, l = tid & 63;  // w in 0..7
  int ln = l & 15, q = l >> 4;
  int j0 = blockIdx.x * 16;
  size_t jrow = (size_t)(j0 + ln) * 2048;

  __shared__ float red[8][80][16];
  __shared__ float rloc[80];
  if (tid < 80) rloc[tid] = 0.f;

  int kbase = w * 256 + q * 8;
  float4 wv[16];
  #pragma unroll
  for (int ks = 0; ks < 8; ++ks) {
    const float4* bp = (const float4*)(Wcls + jrow + kbase + ks * 32);
    wv[2 * ks] = bp[0];
    wv[2 * ks + 1] = bp[1];
  }
  f32x4 acc[5] = {};
  #pragma unroll
  for (int ks = 0; ks < 8; ++ks) {
    int kq = kbase + ks * 32;
    bf16x8 bfrag = cvt8(wv[2 * ks], wv[2 * ks + 1]);
    #pragma unroll
    for (int mt = 0; mt < 5; ++mt) {
      bf16x8 afrag = *(const bf16x8*)(x2 + (size_t)(mt * 16 + ln) * 2048 + kq);
      acc[mt] = MFMA16(afrag, bfrag, acc[mt]);
    }
  }
  #pragma unroll
  for (int mt = 0; mt < 5; ++mt)
    #pragma unroll
    for (int reg = 0; reg < 4; ++reg)
      red[w][mt * 16 + q * 4 + reg][ln] = acc[mt][reg];
  __syncthreads();

  for (int o = tid; o < 1280; o += 512) {
    int c = o >> 4, jj = o & 15;
    float v = bcls[j0 + jj];
    #pragma unroll
    for (int ww = 0; ww < 8; ++ww) v += red[ww][c][jj];
    P[(size_t)c * 8000 + j0 + jj] = (bf16_t)v;
    atomicAdd(&rloc[c], bimg[j0 + jj] * v);
  }
  __syncthreads();
  if (tid < 80) atomicAdd(&r[tid], rloc[tid]);
}

// ---- Hp[jc] = P j-slice @ Wimg : grid 800 = 32 nc x 25 jc ---- (R6 verbatim)
__global__ __launch_bounds__(256) void k_hmat(
    const float* __restrict__ Wimg, const bf16_t* __restrict__ P, float* __restrict__ Hp) {
  int tid = threadIdx.x;
  int w = tid >> 6, l = tid & 63;
  int ln = l & 15, q = l >> 4;
  int nc = blockIdx.x & 31, jc = blockIdx.x >> 5;  // jc 0..24
  const float* wbase = Wimg + (size_t)(jc * 320) * 2048 + nc * 64;

  __shared__ float Bs[2][32][66];
  float4 pv[2];
  #pragma unroll
  for (int it = 0; it < 2; ++it) {
    int slot = tid + it * 256, jr = slot >> 4, nq = slot & 15;
    pv[it] = *(const float4*)(wbase + (size_t)jr * 2048 + nq * 4);
  }
  f32x4 acc[5] = {};
  for (int s = 0; s < 10; ++s) {
    #pragma unroll
    for (int it = 0; it < 2; ++it) {
      int slot = tid + it * 256, jr = slot >> 4, nq = slot & 15;
      *(float4*)&Bs[s & 1][jr][nq * 4] = pv[it];
    }
    __syncthreads();
    if (s < 9) {
      #pragma unroll
      for (int it = 0; it < 2; ++it) {
        int slot = tid + it * 256, jr = slot >> 4, nq = slot & 15;
        pv[it] = *(const float4*)(wbase + (size_t)((s + 1) * 32 + jr) * 2048 + nq * 4);
      }
    }
    int j0 = jc * 320 + s * 32;
    bf16x8 bfrag;
    #pragma unroll
    for (int jj = 0; jj < 8; ++jj) bfrag[jj] = (bf16_t)Bs[s & 1][q * 8 + jj][w * 16 + ln];
    #pragma unroll
    for (int mt = 0; mt < 5; ++mt) {
      bf16x8 afrag = *(const bf16x8*)(P + (size_t)(mt * 16 + ln) * 8000 + j0 + q * 8);
      acc[mt] = MFMA16(afrag, bfrag, acc[mt]);
    }
  }
  float* hp = Hp + (size_t)jc * 163840 + nc * 64 + w * 16 + ln;
  #pragma unroll
  for (int mt = 0; mt < 5; ++mt)
    #pragma unroll
    for (int reg = 0; reg < 4; ++reg)
      hp[(size_t)(mt * 16 + q * 4 + reg) * 2048] = acc[mt][reg];
}

// ---- H = sum_25 Hp ---- (R6 verbatim)
__global__ void k_hred(const float* __restrict__ Hp, float* __restrict__ H) {
  int i = blockIdx.x * 256 + threadIdx.x;  // 163840
  float s = 0.f;
  #pragma unroll
  for (int p = 0; p < 25; ++p) s += Hp[(size_t)p * 163840 + i];
  H[i] = s;
}

// ---- out[b][c] = sum_k feature[b][k]*H[c][k] + r[c] : [1024,80] ----
// register-prefetch feat (latency fix); 8-wave K-split, LDS reduce, direct store
__global__ __launch_bounds__(512) void k_out(
    const float* __restrict__ feat, const float* __restrict__ H,
    const float* __restrict__ r, float* __restrict__ out) {
  int tid = threadIdx.x;
  int w = tid >> 6, l = tid & 63;  // w in 0..7
  int ln = l & 15, q = l >> 4;
  int m0 = blockIdx.x * 16;
  size_t frow = (size_t)(m0 + ln) * 2048;

  __shared__ float red[8][16][80];
  int kbase = w * 256 + q * 8;
  float4 fv[16];
  #pragma unroll
  for (int ks = 0; ks < 8; ++ks) {
    const float4* ap = (const float4*)(feat + frow + kbase + ks * 32);
    fv[2 * ks] = ap[0];
    fv[2 * ks + 1] = ap[1];
  }
  f32x4 acc[5] = {};
  #pragma unroll
  for (int ks = 0; ks < 8; ++ks) {
    int kq = kbase + ks * 32;
    bf16x8 afrag = cvt8(fv[2 * ks], fv[2 * ks + 1]);
    #pragma unroll
    for (int nt = 0; nt < 5; ++nt) {
      const float4* hp = (const float4*)(H + (size_t)(nt * 16 + ln) * 2048 + kq);
      bf16x8 bfrag = cvt8(hp[0], hp[1]);
      acc[nt] = MFMA16(afrag, bfrag, acc[nt]);
    }
  }
  #pragma unroll
  for (int nt = 0; nt < 5; ++nt)
    #pragma unroll
    for (int reg = 0; reg < 4; ++reg)
      red[w][q * 4 + reg][nt * 16 + ln] = acc[nt][reg];
  __syncthreads();
  for (int o = tid; o < 1280; o += 512) {
    int mm = o / 80, c = o % 80;
    float v = r[c];
    #pragma unroll
    for (int ww = 0; ww < 8; ++ww) v += red[ww][mm][c];
    out[(m0 + mm) * 80 + c] = v;
  }
}

extern "C" void kernel_launch(void* const* d_in, const int* in_sizes, int n_in,
                              void* d_out, int out_size, void* d_ws, size_t ws_size,
                              hipStream_t stream) {
  const float* feature = (const float*)d_in[0];
  const float* inp     = (const float*)d_in[1];  // [1,80,300]
  const float* A       = (const float*)d_in[2];
  const float* Wgc1    = (const float*)d_in[3];
  const float* Wgc2    = (const float*)d_in[4];
  const float* Wimg    = (const float*)d_in[5];
  const float* bimg    = (const float*)d_in[6];
  const float* Wcls    = (const float*)d_in[7];
  const float* bcls    = (const float*)d_in[8];
  float* out = (float*)d_out;

  char* ws = (char*)d_ws;
  float*  adj = (float*)(ws + 0);          //  80x80    fp32     25,600
  float*  t1  = (float*)(ws + 25600);      //  80x1024  fp32    327,680
  bf16_t* y   = (bf16_t*)(ws + 353280);    //  80x1024  bf16    163,840
  bf16_t* x2  = (bf16_t*)(ws + 517120);    //  80x2048  bf16    327,680
  bf16_t* P   = (bf16_t*)(ws + 844800);    //  80x8000  bf16  1,280,000
  float*  H   = (float*)(ws + 2124800);    //  80x2048  fp32    655,360
  float*  r   = (float*)(ws + 2780160);    //  80       fp32        320
  bf16_t* x0b = (bf16_t*)(ws + 2780480);   //  80x384   bf16     61,440
  float*  t2p = (float*)(ws + 2841920);    //  8x163840 fp32  5,242,880
  float*  Hp  = (float*)(ws + 8084800);    // 25x163840 fp32 16,384,000
                                           // total ~24.5 MB

  k_setup<<<121, 256, 0, stream>>>(A, inp, adj, r, x0b);
  k_gc1m<<<64, 256, 0, stream>>>(x0b, Wgc1, t1);
  k_adj2<<<16, 256, 0, stream>>>(adj, t1, y);
  k_gc2m<<<256, 256, 0, stream>>>(y, Wgc2, t2p);
  k_redcvt<<<640, 256, 0, stream>>>(t2p, x2);
  k_clsproj<<<500, 512, 0, stream>>>(Wcls, bcls, bimg, x2, P, r);
  k_hmat<<<800, 256, 0, stream>>>(Wimg, P, Hp);
  k_hred<<<640, 256, 0, stream>>>(Hp, H);
  k_out<<<64, 512, 0, stream>>>(feature, H, r, out);
}